// Round 1
// baseline (489.924 us; speedup 1.0000x reference)
//
#include <hip/hip_runtime.h>
#include <hip/hip_bf16.h>

#define D_MODEL 512
#define N_HEADS 8
#define HEAD_DIM 64
#define BATCH 2
#define SEQ 4096
#define M_ROWS (BATCH*SEQ)   // 8192

typedef __attribute__((ext_vector_type(8))) short short8;
typedef __attribute__((ext_vector_type(4))) float f32x4;

__device__ inline short f2bf(float f) {
  union { float f; unsigned u; } v; v.f = f;
  unsigned u = v.u;
  unsigned r = u + 0x7FFFu + ((u >> 16) & 1u);
  return (short)(r >> 16);
}
__device__ inline float bf2f(short s) {
  union { unsigned u; float f; } v; v.u = ((unsigned)(unsigned short)s) << 16;
  return v.f;
}

// ---------------- prep: casts + rope tables ----------------
__global__ void prep_kernel(const float* __restrict__ x,
                            const float* __restrict__ Wq,
                            const float* __restrict__ Wk,
                            const float* __restrict__ Wv,
                            const float* __restrict__ Wo,
                            short* __restrict__ xb,
                            short* __restrict__ Wqkv,
                            short* __restrict__ Wob,
                            float* __restrict__ cosT,
                            float* __restrict__ sinT) {
  int i = blockIdx.x * blockDim.x + threadIdx.x;
  if (i < M_ROWS * D_MODEL) xb[i] = f2bf(x[i]);
  if (i < 3 * D_MODEL * D_MODEL) {
    int t = i >> 18;            // which W (262144 each)
    int r = i & 262143;
    const float* W = (t == 0) ? Wq : ((t == 1) ? Wk : Wv);
    Wqkv[i] = f2bf(W[r]);
  }
  if (i < D_MODEL * D_MODEL) Wob[i] = f2bf(Wo[i]);
  if (i < SEQ * 32) {
    int s = i >> 5, p = i & 31;
    float e = (float)(2 * p) * (1.0f / 64.0f);
    float inv = powf(10000.0f, -e);
    float ang = (float)s * inv;
    float sv, cv;
    sincosf(ang, &sv, &cv);
    cosT[i] = cv; sinT[i] = sv;
  }
}

// ---------------- rope (in place on bf16 Q/K in [BH,S,64]) ----------------
__global__ void rope_kernel(short* __restrict__ Qb, short* __restrict__ Kb,
                            const float* __restrict__ cosT,
                            const float* __restrict__ sinT) {
  int i = blockIdx.x * blockDim.x + threadIdx.x;  // 2 * 16*4096*32 total
  int t = i >> 21;
  int r = i & ((1 << 21) - 1);
  int p = r & 31;
  int s = (r >> 5) & 4095;
  short* buf = t ? Kb : Qb;
  int base = (r >> 5) * 64 + 2 * p;
  float c = cosT[s * 32 + p], sn = sinT[s * 32 + p];
  float e = bf2f(buf[base]), o = bf2f(buf[base + 1]);
  buf[base]     = f2bf(e * c - o * sn);
  buf[base + 1] = f2bf(e * sn + o * c);
}

// ---------------- GEMM: y[m,n] = sum_k A[m,k]*B[n,k] (B in n,k = W layout) ----
// MODE 0: N=1536 fused QKV -> scatter bf16 into Q/K/V [BH][S][64]
// MODE 1: N=512 -> fp32 d_out
template<int MODE>
__global__ __launch_bounds__(256) void gemm_kernel(const short* __restrict__ A,
                                                   const short* __restrict__ B,
                                                   float* __restrict__ out_f,
                                                   short* __restrict__ Qb,
                                                   short* __restrict__ Kb,
                                                   short* __restrict__ Vb) {
  __shared__ short As[128][72];
  __shared__ short Bs[128][72];
  const int m0 = blockIdx.x * 128;
  const int n0 = blockIdx.y * 128;
  const int tid = threadIdx.x;
  const int lane = tid & 63, wid = tid >> 6;
  const int wm = wid >> 1, wn = wid & 1;
  const int l15 = lane & 15, g = lane >> 4;
  const int Kdim = 512;

  f32x4 acc[4][4] = {};

  for (int kt = 0; kt < Kdim; kt += 64) {
    __syncthreads();
    for (int it = 0; it < 4; ++it) {
      int c = it * 256 + tid;
      int row = c >> 3, col = (c & 7) << 3;
      *(short8*)&As[row][col] = *(const short8*)&A[(m0 + row) * Kdim + kt + col];
      *(short8*)&Bs[row][col] = *(const short8*)&B[(n0 + row) * Kdim + kt + col];
    }
    __syncthreads();
    for (int kk = 0; kk < 64; kk += 32) {
      short8 a[4], b[4];
      for (int mi = 0; mi < 4; ++mi)
        a[mi] = *(const short8*)&As[wm * 64 + mi * 16 + l15][kk + (g << 3)];
      for (int ni = 0; ni < 4; ++ni)
        b[ni] = *(const short8*)&Bs[wn * 64 + ni * 16 + l15][kk + (g << 3)];
      for (int mi = 0; mi < 4; ++mi)
        for (int ni = 0; ni < 4; ++ni)
          acc[mi][ni] = __builtin_amdgcn_mfma_f32_16x16x32_bf16(a[mi], b[ni], acc[mi][ni], 0, 0, 0);
    }
  }

  for (int mi = 0; mi < 4; ++mi)
    for (int ni = 0; ni < 4; ++ni)
      for (int r = 0; r < 4; ++r) {
        int row_g = m0 + wm * 64 + mi * 16 + (g << 2) + r;
        int col_g = n0 + wn * 64 + ni * 16 + l15;
        float v = acc[mi][ni][r];
        if (MODE == 1) {
          out_f[row_g * 512 + col_g] = v;
        } else {
          int t = col_g >> 9, cc = col_g & 511;
          int h = cc >> 6, d = cc & 63;
          int bb = row_g >> 12, ss = row_g & 4095;
          short* dst = (t == 0) ? Qb : ((t == 1) ? Kb : Vb);
          dst[(((bb << 3) + h) * SEQ + ss) * 64 + d] = f2bf(v);
        }
      }
}

// ---------------- flash attention (causal) ----------------
// Q,K,V: bf16 [BH=16][S=4096][64]; O: bf16 [B*S=8192][512] (col = h*64+d)
__global__ __launch_bounds__(256) void attn_kernel(const short* __restrict__ Q,
                                                   const short* __restrict__ K,
                                                   const short* __restrict__ V,
                                                   short* __restrict__ O) {
  __shared__ short P_lds[4][16][32];
  const int qt = blockIdx.x, bh = blockIdx.y;
  const int tid = threadIdx.x, lane = tid & 63, w = tid >> 6;
  const int q0 = qt * 64 + w * 16;
  const long base = (long)bh * SEQ * 64;
  const int l15 = lane & 15, g = lane >> 4;
  const float scale = 0.125f;

  short8 aq[2];
  for (int kk = 0; kk < 2; ++kk)
    aq[kk] = *(const short8*)&Q[base + (q0 + l15) * 64 + kk * 32 + (g << 3)];

  f32x4 o_acc[4] = {};
  float m_r[4], l_r[4];
  for (int r = 0; r < 4; ++r) { m_r[r] = -__builtin_inff(); l_r[r] = 0.f; }

  const int kv_end = q0 + 16;  // causal: kv <= q, rows q0..q0+15
  for (int kv0 = 0; kv0 < kv_end; kv0 += 32) {
    f32x4 sf[2] = {};
    for (int f = 0; f < 2; ++f) {
      short8 bk0 = *(const short8*)&K[base + (kv0 + f * 16 + l15) * 64 + (g << 3)];
      short8 bk1 = *(const short8*)&K[base + (kv0 + f * 16 + l15) * 64 + 32 + (g << 3)];
      sf[f] = __builtin_amdgcn_mfma_f32_16x16x32_bf16(aq[0], bk0, sf[f], 0, 0, 0);
      sf[f] = __builtin_amdgcn_mfma_f32_16x16x32_bf16(aq[1], bk1, sf[f], 0, 0, 0);
    }
    float pm[4], sv[2][4];
    for (int r = 0; r < 4; ++r) {
      int qrow = q0 + (g << 2) + r;
      pm[r] = -__builtin_inff();
      for (int f = 0; f < 2; ++f) {
        int kvc = kv0 + f * 16 + l15;
        float v = (kvc <= qrow) ? sf[f][r] * scale : -__builtin_inff();
        sv[f][r] = v;
        pm[r] = fmaxf(pm[r], v);
      }
    }
    for (int off = 1; off < 16; off <<= 1)
      for (int r = 0; r < 4; ++r)
        pm[r] = fmaxf(pm[r], __shfl_xor(pm[r], off));

    float p[2][4], rs[4];
    for (int r = 0; r < 4; ++r) {
      float mn = fmaxf(m_r[r], pm[r]);
      float alpha = expf(m_r[r] - mn);
      m_r[r] = mn;
      l_r[r] *= alpha;
      rs[r] = 0.f;
      for (int f = 0; f < 2; ++f) {
        float pv = expf(sv[f][r] - mn);
        p[f][r] = pv;
        rs[r] += pv;
      }
      for (int db = 0; db < 4; ++db) o_acc[db][r] *= alpha;
    }
    for (int off = 1; off < 16; off <<= 1)
      for (int r = 0; r < 4; ++r)
        rs[r] += __shfl_xor(rs[r], off);
    for (int r = 0; r < 4; ++r) l_r[r] += rs[r];

    for (int f = 0; f < 2; ++f)
      for (int r = 0; r < 4; ++r)
        P_lds[w][(g << 2) + r][f * 16 + l15] = f2bf(p[f][r]);

    short8 pa = *(const short8*)&P_lds[w][l15][g << 3];
    for (int db = 0; db < 4; ++db) {
      short8 bv;
      for (int i = 0; i < 8; ++i)
        bv[i] = V[base + (kv0 + (g << 3) + i) * 64 + db * 16 + l15];
      o_acc[db] = __builtin_amdgcn_mfma_f32_16x16x32_bf16(pa, bv, o_acc[db], 0, 0, 0);
    }
  }

  const int bb = bh >> 3, h = bh & 7;
  for (int db = 0; db < 4; ++db)
    for (int r = 0; r < 4; ++r) {
      int s_g = q0 + (g << 2) + r;
      float v = o_acc[db][r] / l_r[r];
      O[((long)(bb * SEQ + s_g)) * 512 + h * 64 + db * 16 + l15] = f2bf(v);
    }
}

extern "C" void kernel_launch(void* const* d_in, const int* in_sizes, int n_in,
                              void* d_out, int out_size, void* d_ws, size_t ws_size,
                              hipStream_t stream) {
  const float* x  = (const float*)d_in[0];
  const float* Wq = (const float*)d_in[1];
  const float* Wk = (const float*)d_in[2];
  const float* Wv = (const float*)d_in[3];
  const float* Wo = (const float*)d_in[4];

  char* ws = (char*)d_ws;
  size_t off = 0;
  auto alloc = [&](size_t bytes) {
    void* p = ws + off;
    off += (bytes + 255) & ~(size_t)255;
    return p;
  };
  short* xb   = (short*)alloc((size_t)M_ROWS * 512 * 2);
  short* Wqkv = (short*)alloc((size_t)1536 * 512 * 2);
  short* Wob  = (short*)alloc((size_t)512 * 512 * 2);
  float* cosT = (float*)alloc((size_t)SEQ * 32 * 4);
  float* sinT = (float*)alloc((size_t)SEQ * 32 * 4);
  short* Qb   = (short*)alloc((size_t)16 * SEQ * 64 * 2);
  short* Kb   = (short*)alloc((size_t)16 * SEQ * 64 * 2);
  short* Vb   = (short*)alloc((size_t)16 * SEQ * 64 * 2);
  short* Obuf = (short*)alloc((size_t)M_ROWS * 512 * 2);

  prep_kernel<<<16384, 256, 0, stream>>>(x, Wq, Wk, Wv, Wo, xb, Wqkv, Wob, cosT, sinT);
  gemm_kernel<0><<<dim3(64, 12), 256, 0, stream>>>(xb, Wqkv, nullptr, Qb, Kb, Vb);
  rope_kernel<<<16384, 256, 0, stream>>>(Qb, Kb, cosT, sinT);
  attn_kernel<<<dim3(SEQ / 64, 16), 256, 0, stream>>>(Qb, Kb, Vb, Obuf);
  gemm_kernel<1><<<dim3(64, 4), 256, 0, stream>>>(Obuf, Wob, (float*)d_out, nullptr, nullptr, nullptr);
}